// Round 1
// baseline (127.184 us; speedup 1.0000x reference)
//
#include <hip/hip_runtime.h>

#define NUSR 8192
#define HDIM 256

typedef __attribute__((ext_vector_type(8))) __bf16 bf16x8;
typedef __attribute__((ext_vector_type(4))) float f32x4;

union frag_u { bf16x8 v; unsigned short u[8]; };

// f32 -> bf16 round-to-nearest-even (inputs are finite randoms; no NaN path needed)
__device__ __forceinline__ unsigned short f2bf(float f) {
  unsigned u = __builtin_bit_cast(unsigned, f);
  u += 0x7FFFu + ((u >> 16) & 1u);
  return (unsigned short)(u >> 16);
}

__device__ __forceinline__ float sigmoidf_fast(float x) {
  // sigmoid(x) = 1/(1+e^-x); exp2/rcp HW approx, saturates to 0/1 at |x| large
  float e = __builtin_amdgcn_exp2f(x * -1.44269504088896340736f);
  return __builtin_amdgcn_rcpf(1.0f + e);
}

// ---------------------------------------------------------------------------
// k1: Z = y_a @ W (bf16 out), c[i] = y_a[i].b, ybf = bf16(y_b)
// grid (64,4): x = 128-row band, y = 64-col chunk of t-dim
// ---------------------------------------------------------------------------
__global__ __launch_bounds__(256) void k1_proj(
    const float* __restrict__ ya, const float* __restrict__ yb,
    const float* __restrict__ W, const float* __restrict__ bvec,
    unsigned short* __restrict__ Zbf, unsigned short* __restrict__ ybf,
    float* __restrict__ cvec)
{
  __shared__ __align__(16) unsigned short wt[64 * 264]; // Wt[tcol][s], stride 264 (pad 8)
  const int tid  = threadIdx.x;
  const int lane = tid & 63;
  const int w    = tid >> 6;
  const int quad = lane >> 4;
  const int l15  = lane & 15;
  const int bx = blockIdx.x;
  const int by = blockIdx.y;
  const int bid = by * 64 + bx; // 0..255

  // ---- convert this block's share of y_b to bf16 (8192 elements)
  {
    const float4* src = (const float4*)yb + (size_t)bid * 2048;
    unsigned short* dst = ybf + (size_t)bid * 8192;
#pragma unroll
    for (int i = 0; i < 8; ++i) {
      float4 v = src[i * 256 + tid];
      ushort4 o;
      o.x = f2bf(v.x); o.y = f2bf(v.y); o.z = f2bf(v.z); o.w = f2bf(v.w);
      *(ushort4*)(dst + (size_t)(i * 256 + tid) * 4) = o;
    }
  }

  // ---- stage W^T chunk: wt[tcol][s] = W[s][by*64+tcol] as bf16
  for (int p = 0; p < 64; ++p) {
    int lin = p * 256 + tid;
    int s = lin >> 6;        // 0..255
    int tc = lin & 63;       // 0..63
    wt[tc * 264 + s] = f2bf(W[s * 256 + by * 64 + tc]);
  }
  __syncthreads();

  const int rbase = bx * 128 + w * 32;

  // ---- A-frags (y_a rows, converted in-register) + c partials
  frag_u A[2][8];
  float cpart[2] = {0.f, 0.f};
#pragma unroll
  for (int h = 0; h < 2; ++h) {
    const float* yarow = ya + (size_t)(rbase + h * 16 + l15) * HDIM;
#pragma unroll
    for (int kb = 0; kb < 8; ++kb) {
      const int k0 = kb * 32 + quad * 8;
      float vv[8];
#pragma unroll
      for (int j = 0; j < 8; ++j) vv[j] = yarow[k0 + j];
#pragma unroll
      for (int j = 0; j < 8; ++j) A[h][kb].u[j] = f2bf(vv[j]);
#pragma unroll
      for (int j = 0; j < 8; ++j) cpart[h] += vv[j] * bvec[k0 + j];
    }
  }
  // reduce c over the 4 quad-groups (lanes l, l^16, l^32, l^48)
#pragma unroll
  for (int off = 16; off < 64; off <<= 1) {
    cpart[0] += __shfl_xor(cpart[0], off, 64);
    cpart[1] += __shfl_xor(cpart[1], off, 64);
  }
  if (by == 0 && lane < 16) {
    cvec[rbase + lane]      = cpart[0];
    cvec[rbase + 16 + lane] = cpart[1];
  }

  // ---- MFMA: Z[rbase..+31][by*64..+63]
#pragma unroll
  for (int tt = 0; tt < 4; ++tt) {
    f32x4 a0 = {0.f,0.f,0.f,0.f}, a1 = {0.f,0.f,0.f,0.f};
#pragma unroll
    for (int kb = 0; kb < 8; ++kb) {
      bf16x8 bfrag = *(const bf16x8*)&wt[(tt * 16 + l15) * 264 + kb * 32 + quad * 8];
      a0 = __builtin_amdgcn_mfma_f32_16x16x32_bf16(A[0][kb].v, bfrag, a0, 0, 0, 0);
      a1 = __builtin_amdgcn_mfma_f32_16x16x32_bf16(A[1][kb].v, bfrag, a1, 0, 0, 0);
    }
    const int col = by * 64 + tt * 16 + l15;
#pragma unroll
    for (int r = 0; r < 4; ++r) {
      // C/D layout (m89-verified): col = lane&15, row = quad*4 + r
      Zbf[(size_t)(rbase + quad * 4 + r) * HDIM + col]      = f2bf(a0[r]);
      Zbf[(size_t)(rbase + 16 + quad * 4 + r) * HDIM + col] = f2bf(a1[r]);
    }
  }
}

// ---------------------------------------------------------------------------
// k2: s[i] += sum_j sigmoid(Z[i].y_b[j] + c[i]) over this block's col range
// grid (64,8): x = 128-row band (4 waves x 32 rows), y = 1024-col chunk
// ---------------------------------------------------------------------------
__global__ __launch_bounds__(256) void k2_score(
    const unsigned short* __restrict__ Zbf, const unsigned short* __restrict__ ybf,
    const float* __restrict__ cvec, float* __restrict__ svec)
{
  __shared__ __align__(16) unsigned short bs[64 * 264]; // ybf tile [col][k], stride 264
  const int tid  = threadIdx.x;
  const int lane = tid & 63;
  const int w    = tid >> 6;
  const int quad = lane >> 4;
  const int l15  = lane & 15;
  const int rbase = blockIdx.x * 128 + w * 32;
  const int cbase = blockIdx.y * 1024;

  // A-frags: 32 rows of Z, full K=256, held in registers (64 VGPRs)
  frag_u A[2][8];
#pragma unroll
  for (int h = 0; h < 2; ++h)
#pragma unroll
    for (int kb = 0; kb < 8; ++kb)
      A[h][kb].v = *(const bf16x8*)&Zbf[(size_t)(rbase + h * 16 + l15) * HDIM + kb * 32 + quad * 8];

  float crow[2][4];
#pragma unroll
  for (int h = 0; h < 2; ++h)
#pragma unroll
    for (int r = 0; r < 4; ++r)
      crow[h][r] = cvec[rbase + h * 16 + quad * 4 + r];

  float rs[2][4] = {{0.f,0.f,0.f,0.f},{0.f,0.f,0.f,0.f}};

  for (int st = 0; st < 16; ++st) {
    __syncthreads(); // previous tile's reads complete before overwrite
    {
      const uint4* src = (const uint4*)(ybf + (size_t)(cbase + st * 64) * HDIM);
#pragma unroll
      for (int p = 0; p < 8; ++p) {
        int lin = p * 256 + tid;
        int row = lin >> 5, ch = lin & 31;
        *(uint4*)&bs[row * 264 + ch * 8] = src[row * 32 + ch];
      }
    }
    __syncthreads();
#pragma unroll
    for (int tt = 0; tt < 4; ++tt) {
      f32x4 a0 = {0.f,0.f,0.f,0.f}, a1 = {0.f,0.f,0.f,0.f};
#pragma unroll
      for (int kb = 0; kb < 8; ++kb) {
        bf16x8 bfrag = *(const bf16x8*)&bs[(tt * 16 + l15) * 264 + kb * 32 + quad * 8];
        a0 = __builtin_amdgcn_mfma_f32_16x16x32_bf16(A[0][kb].v, bfrag, a0, 0, 0, 0);
        a1 = __builtin_amdgcn_mfma_f32_16x16x32_bf16(A[1][kb].v, bfrag, a1, 0, 0, 0);
      }
#pragma unroll
      for (int r = 0; r < 4; ++r) {
        rs[0][r] += sigmoidf_fast(a0[r] + crow[0][r]);
        rs[1][r] += sigmoidf_fast(a1[r] + crow[1][r]);
      }
    }
  }

  // reduce over the 16 col-lanes within each quad group
#pragma unroll
  for (int off = 1; off < 16; off <<= 1) {
#pragma unroll
    for (int h = 0; h < 2; ++h)
#pragma unroll
      for (int r = 0; r < 4; ++r)
        rs[h][r] += __shfl_xor(rs[h][r], off, 64);
  }
  if (l15 == 0) {
#pragma unroll
    for (int h = 0; h < 2; ++h)
#pragma unroll
      for (int r = 0; r < 4; ++r)
        atomicAdd(&svec[rbase + h * 16 + quad * 4 + r], rs[h][r]);
  }
}

// ---------------------------------------------------------------------------
// k3: out[i][k] = s[i] / 256
// ---------------------------------------------------------------------------
__global__ __launch_bounds__(256) void k3_bcast(
    const float* __restrict__ svec, float* __restrict__ out)
{
  int idx = blockIdx.x * 256 + threadIdx.x; // float4 index, 0..524287
  int row = idx >> 6;                        // 64 float4 per row
  float v = svec[row] * (1.0f / 256.0f);
  float4 o = {v, v, v, v};
  ((float4*)out)[idx] = o;
}

extern "C" void kernel_launch(void* const* d_in, const int* in_sizes, int n_in,
                              void* d_out, int out_size, void* d_ws, size_t ws_size,
                              hipStream_t stream) {
  (void)in_sizes; (void)n_in; (void)out_size;
  const float* ya = (const float*)d_in[0];
  const float* yb = (const float*)d_in[1];
  const float* W  = (const float*)d_in[2];
  const float* bv = (const float*)d_in[3];
  float* out = (float*)d_out;

  char* ws = (char*)d_ws;
  unsigned short *Zbf, *ybf;
  float *cvec, *svec;
  const size_t need = (8ull << 20) + (64ull << 10);
  if (ws_size >= need) {
    Zbf  = (unsigned short*)ws;
    ybf  = (unsigned short*)(ws + (4 << 20));
    cvec = (float*)(ws + (8 << 20));
    svec = (float*)(ws + (8 << 20) + (32 << 10));
  } else {
    // fall back: stash bf16 scratch in d_out (8 MB, fully rewritten by k3)
    Zbf  = (unsigned short*)d_out;
    ybf  = (unsigned short*)((char*)d_out + (4 << 20));
    cvec = (float*)ws;
    svec = (float*)(ws + (32 << 10));
  }

  hipMemsetAsync(svec, 0, NUSR * sizeof(float), stream);
  k1_proj<<<dim3(64, 4), 256, 0, stream>>>(ya, yb, W, bv, Zbf, ybf, cvec);
  k2_score<<<dim3(64, 8), 256, 0, stream>>>(Zbf, ybf, cvec, svec);
  k3_bcast<<<2048, 256, 0, stream>>>(svec, out);
}